// Round 1
// baseline (3951.400 us; speedup 1.0000x reference)
//
#include <hip/hip_runtime.h>
#include <hip/hip_bf16.h>
#include <math.h>

// Model constants (fixed by the reference)
constexpr int L = 4, D = 512, H = 8, DH = 64, FF = 2048, V = 32000, B = 2, T = 1024, WD = 32, BAND = 128;
constexpr float SCALE = 0.125f;  // 1/sqrt(64)

// ---------------------------------------------------------------------------
// Embedding: x[b,t,:] = wte[idx[b,t],:] + wpe[t,:]
// ---------------------------------------------------------------------------
__global__ __launch_bounds__(256) void embed_k(const int* __restrict__ idx,
                                               const float* __restrict__ wte,
                                               const float* __restrict__ wpe,
                                               float* __restrict__ x) {
    int row = blockIdx.x;          // 0..B*T-1
    int t = row % T;
    int token = idx[row];
    const float* we = wte + (size_t)token * D;
    const float* pe = wpe + (size_t)t * D;
    float* xo = x + (size_t)row * D;
    for (int d = threadIdx.x; d < D; d += 256) xo[d] = we[d] + pe[d];
}

// ---------------------------------------------------------------------------
// LayerNorm over D=512, one block (256 thr) per row
// ---------------------------------------------------------------------------
__global__ __launch_bounds__(256) void ln_k(const float* __restrict__ x,
                                            const float* __restrict__ g,
                                            const float* __restrict__ b,
                                            float* __restrict__ o) {
    int row = blockIdx.x;
    const float* xr = x + (size_t)row * D;
    int d0 = threadIdx.x, d1 = threadIdx.x + 256;
    float v0 = xr[d0], v1 = xr[d1];
    float s = v0 + v1, ss = v0 * v0 + v1 * v1;
    for (int off = 32; off > 0; off >>= 1) {
        s  += __shfl_down(s, off);
        ss += __shfl_down(ss, off);
    }
    __shared__ float red[2][4];
    int wid = threadIdx.x >> 6;
    if ((threadIdx.x & 63) == 0) { red[0][wid] = s; red[1][wid] = ss; }
    __syncthreads();
    s  = red[0][0] + red[0][1] + red[0][2] + red[0][3];
    ss = red[1][0] + red[1][1] + red[1][2] + red[1][3];
    float mean = s * (1.0f / D);
    float var  = ss * (1.0f / D) - mean * mean;
    float rstd = rsqrtf(var + 1e-5f);
    float* orow = o + (size_t)row * D;
    orow[d0] = (v0 - mean) * rstd * g[d0] + b[d0];
    orow[d1] = (v1 - mean) * rstd * g[d1] + b[d1];
}

// ---------------------------------------------------------------------------
// Tiled fp32 GEMM: C[m,n] = sum_k A[m,k] * W[n,k] (+bias) (+residual)
// A: (M,K) row-major, W: (N,K) row-major. 64x64 tile, BK=16, 256 thr, 4x4/thread.
// EPI: 0 = +bias; 1 = +bias+residual; 2 = plain
// All of M,N multiples of 64; K multiple of 16 (true for every call here).
// ---------------------------------------------------------------------------
template <int EPI>
__global__ __launch_bounds__(256) void gemm_k(const float* __restrict__ A,
                                              const float* __restrict__ W,
                                              const float* __restrict__ bias,
                                              const float* __restrict__ res,
                                              float* __restrict__ C,
                                              int M, int N, int K) {
    __shared__ __align__(16) float As[16][68];
    __shared__ __align__(16) float Ws[16][68];
    int m0 = blockIdx.y * 64, n0 = blockIdx.x * 64;
    int tid = threadIdx.x;
    int lr = tid >> 2;             // 0..63 tile row
    int lk = (tid & 3) * 4;        // 0,4,8,12
    int tx = tid & 15, ty = tid >> 4;
    float acc[4][4] = {};
    for (int k0 = 0; k0 < K; k0 += 16) {
        float4 a = *(const float4*)&A[(size_t)(m0 + lr) * K + k0 + lk];
        float4 w = *(const float4*)&W[(size_t)(n0 + lr) * K + k0 + lk];
        __syncthreads();
        As[lk + 0][lr] = a.x; As[lk + 1][lr] = a.y; As[lk + 2][lr] = a.z; As[lk + 3][lr] = a.w;
        Ws[lk + 0][lr] = w.x; Ws[lk + 1][lr] = w.y; Ws[lk + 2][lr] = w.z; Ws[lk + 3][lr] = w.w;
        __syncthreads();
#pragma unroll
        for (int k = 0; k < 16; k++) {
            float4 av = *(const float4*)&As[k][ty * 4];
            float4 wv = *(const float4*)&Ws[k][tx * 4];
            float ar[4] = {av.x, av.y, av.z, av.w};
            float wr[4] = {wv.x, wv.y, wv.z, wv.w};
#pragma unroll
            for (int i = 0; i < 4; i++)
#pragma unroll
                for (int j = 0; j < 4; j++) acc[i][j] += ar[i] * wr[j];
        }
    }
#pragma unroll
    for (int i = 0; i < 4; i++) {
        int m = m0 + ty * 4 + i;
#pragma unroll
        for (int j = 0; j < 4; j++) {
            int n = n0 + tx * 4 + j;
            float v = acc[i][j];
            if (EPI != 2) v += bias[n];
            if (EPI == 1) v += res[(size_t)m * N + n];
            C[(size_t)m * N + n] = v;
        }
    }
}

// ---------------------------------------------------------------------------
// Fused SWIGLU dual GEMM: ff = silu(A@G^T + gb) * (A@Vw^T + vb)
// ---------------------------------------------------------------------------
__global__ __launch_bounds__(256) void gemm_swiglu_k(const float* __restrict__ A,
                                                     const float* __restrict__ G,
                                                     const float* __restrict__ gb,
                                                     const float* __restrict__ Vw,
                                                     const float* __restrict__ vb,
                                                     float* __restrict__ C,
                                                     int M, int N, int K) {
    __shared__ __align__(16) float As[16][68];
    __shared__ __align__(16) float Gs[16][68];
    __shared__ __align__(16) float Vs[16][68];
    int m0 = blockIdx.y * 64, n0 = blockIdx.x * 64;
    int tid = threadIdx.x;
    int lr = tid >> 2;
    int lk = (tid & 3) * 4;
    int tx = tid & 15, ty = tid >> 4;
    float accg[4][4] = {}, accv[4][4] = {};
    for (int k0 = 0; k0 < K; k0 += 16) {
        float4 a = *(const float4*)&A[(size_t)(m0 + lr) * K + k0 + lk];
        float4 g = *(const float4*)&G[(size_t)(n0 + lr) * K + k0 + lk];
        float4 v = *(const float4*)&Vw[(size_t)(n0 + lr) * K + k0 + lk];
        __syncthreads();
        As[lk + 0][lr] = a.x; As[lk + 1][lr] = a.y; As[lk + 2][lr] = a.z; As[lk + 3][lr] = a.w;
        Gs[lk + 0][lr] = g.x; Gs[lk + 1][lr] = g.y; Gs[lk + 2][lr] = g.z; Gs[lk + 3][lr] = g.w;
        Vs[lk + 0][lr] = v.x; Vs[lk + 1][lr] = v.y; Vs[lk + 2][lr] = v.z; Vs[lk + 3][lr] = v.w;
        __syncthreads();
#pragma unroll
        for (int k = 0; k < 16; k++) {
            float4 av = *(const float4*)&As[k][ty * 4];
            float4 gv = *(const float4*)&Gs[k][tx * 4];
            float4 vv = *(const float4*)&Vs[k][tx * 4];
            float ar[4] = {av.x, av.y, av.z, av.w};
            float gr[4] = {gv.x, gv.y, gv.z, gv.w};
            float vr[4] = {vv.x, vv.y, vv.z, vv.w};
#pragma unroll
            for (int i = 0; i < 4; i++)
#pragma unroll
                for (int j = 0; j < 4; j++) {
                    accg[i][j] += ar[i] * gr[j];
                    accv[i][j] += ar[i] * vr[j];
                }
        }
    }
#pragma unroll
    for (int i = 0; i < 4; i++) {
        int m = m0 + ty * 4 + i;
#pragma unroll
        for (int j = 0; j < 4; j++) {
            int n = n0 + tx * 4 + j;
            float g = accg[i][j] + gb[n];
            float v = accv[i][j] + vb[n];
            float s = g / (1.0f + __expf(-g));
            C[(size_t)m * N + n] = s * v;
        }
    }
}

// ---------------------------------------------------------------------------
// QK^T: att[b,h,i,j] = SCALE * q[b,i,h,:]·k[b,j,h,:] for all causal (j<=i), all heads
// (DAPE needs ALL heads' raw scores at every causal position, incl. banded-out ones.)
// grid: (T/64 j-tiles, T/16 i-tiles, B*H). 256 thr.
// ---------------------------------------------------------------------------
__global__ __launch_bounds__(256) void qk_k(const float* __restrict__ qkv,
                                            float* __restrict__ att) {
    int bh = blockIdx.z; int b = bh / H, h = bh % H;
    int i0 = blockIdx.y * 16, j0 = blockIdx.x * 64;
    if (j0 > i0 + 15) return;  // fully above the diagonal
    __shared__ __align__(16) float Qs[16][68];
    __shared__ __align__(16) float Ks[64][68];
    int tid = threadIdx.x;
    {
        int r = tid >> 4, d0 = (tid & 15) * 4;
        *(float4*)&Qs[r][d0] = *(const float4*)&qkv[((size_t)(b * T + i0 + r)) * (3 * D) + h * DH + d0];
#pragma unroll
        for (int it = 0; it < 4; it++) {
            int c = (tid >> 4) + it * 16;
            *(float4*)&Ks[c][d0] = *(const float4*)&qkv[((size_t)(b * T + j0 + c)) * (3 * D) + D + h * DH + d0];
        }
    }
    __syncthreads();
    int c = tid & 63;       // j within tile
    int r0 = tid >> 6;      // 0..3, handles rows r0*4 .. r0*4+3
    float acc[4] = {0.f, 0.f, 0.f, 0.f};
#pragma unroll
    for (int d0 = 0; d0 < 64; d0 += 4) {
        float4 kv = *(const float4*)&Ks[c][d0];
#pragma unroll
        for (int q = 0; q < 4; q++) {
            float4 qv = *(const float4*)&Qs[r0 * 4 + q][d0];
            acc[q] += qv.x * kv.x + qv.y * kv.y + qv.z * kv.z + qv.w * kv.w;
        }
    }
    size_t base = ((size_t)(b * H + h) * T) * T;
#pragma unroll
    for (int q = 0; q < 4; q++) {
        int i = i0 + r0 * 4 + q, j = j0 + c;
        if (j <= i) att[base + (size_t)i * T + j] = acc[q] * SCALE;
    }
}

// ---------------------------------------------------------------------------
// DAPE + ALiBi (in place on raw scores): for each causal (b,i,j):
//   s[h] (8 scores) -> hid[w] = silu(s·gw[w]+gb[w]) * (s·vw[w]+vb[w]), w<32
//   lb[h] = hid·ow[h] + ob[h];  att = s + lb - slope_h*(i-j)
// grid: B*T blocks (one per (b,i)), 256 thr loop over j<=i.
// ---------------------------------------------------------------------------
__global__ __launch_bounds__(256) void dape_k(float* __restrict__ att,
                                              const float* __restrict__ gw,
                                              const float* __restrict__ gb,
                                              const float* __restrict__ vw,
                                              const float* __restrict__ vb,
                                              const float* __restrict__ ow,
                                              const float* __restrict__ ob) {
    int bi = blockIdx.x; int b = bi / T, i = bi % T;
    __shared__ float sgw[WD][H], svw[WD][H], sow[H][WD];
    __shared__ float sgb[WD], svb[WD], sob[H];
    int tid = threadIdx.x;
    if (tid < WD * H) {
        int w = tid >> 3, hh = tid & 7;
        sgw[w][hh] = gw[w * (2 * H) + hh];   // only first H cols matter (rest multiply zeros)
        svw[w][hh] = vw[w * (2 * H) + hh];
        sow[hh][w] = ow[hh * WD + w];
    }
    if (tid < WD) { sgb[tid] = gb[tid]; svb[tid] = vb[tid]; }
    if (tid < H) sob[tid] = ob[tid];
    __syncthreads();
    const float slopes[H] = {0.5f, 0.25f, 0.125f, 0.0625f, 0.03125f, 0.015625f, 0.0078125f, 0.00390625f};
    size_t base = (size_t)b * H * T * T + (size_t)i * T;
    for (int j = tid; j <= i; j += 256) {
        float s[H], lb[H];
#pragma unroll
        for (int hh = 0; hh < H; hh++) s[hh] = att[base + (size_t)hh * T * T + j];
#pragma unroll
        for (int hh = 0; hh < H; hh++) lb[hh] = sob[hh];
#pragma unroll
        for (int w = 0; w < WD; w++) {
            float g = sgb[w], v = svb[w];
#pragma unroll
            for (int hh = 0; hh < H; hh++) { g += s[hh] * sgw[w][hh]; v += s[hh] * svw[w][hh]; }
            float hid = (g / (1.0f + __expf(-g))) * v;
#pragma unroll
            for (int hh = 0; hh < H; hh++) lb[hh] += hid * sow[hh][w];
        }
        float diff = (float)(i - j);
#pragma unroll
        for (int hh = 0; hh < H; hh++)
            att[base + (size_t)hh * T * T + j] = s[hh] + lb[hh] - slopes[hh] * diff;
    }
}

// ---------------------------------------------------------------------------
// Row softmax over each head's valid range: even h -> [0,i]; odd h -> [max(0,i-127), i]
// grid: B*H*T blocks, 256 thr.
// ---------------------------------------------------------------------------
__global__ __launch_bounds__(256) void softmax_k(float* __restrict__ att) {
    int id = blockIdx.x;
    int i = id % T;
    int h = (id / T) % H;
    size_t base = (size_t)id * T;
    int jlo = (h & 1) ? max(0, i - (BAND - 1)) : 0;
    int tid = threadIdx.x;
    float mx = -1e30f;
    for (int j = jlo + tid; j <= i; j += 256) mx = fmaxf(mx, att[base + j]);
    for (int off = 32; off > 0; off >>= 1) mx = fmaxf(mx, __shfl_down(mx, off));
    __shared__ float redm[4], reds[4];
    if ((tid & 63) == 0) redm[tid >> 6] = mx;
    __syncthreads();
    mx = fmaxf(fmaxf(redm[0], redm[1]), fmaxf(redm[2], redm[3]));
    float sum = 0.f;
    for (int j = jlo + tid; j <= i; j += 256) {
        float e = __expf(att[base + j] - mx);
        att[base + j] = e;
        sum += e;
    }
    for (int off = 32; off > 0; off >>= 1) sum += __shfl_down(sum, off);
    if ((tid & 63) == 0) reds[tid >> 6] = sum;
    __syncthreads();
    sum = reds[0] + reds[1] + reds[2] + reds[3];
    float inv = 1.0f / sum;
    for (int j = jlo + tid; j <= i; j += 256) att[base + j] *= inv;
}

// ---------------------------------------------------------------------------
// AV: y[b,i,h*64+d] = sum_j p[b,h,i,j] * v[b,j,h,:]   (tiled: 16 i-rows per block)
// grid: (T/16 i-tiles, B*H), 256 thr.
// ---------------------------------------------------------------------------
__global__ __launch_bounds__(256) void av_k(const float* __restrict__ att,
                                            const float* __restrict__ qkv,
                                            float* __restrict__ y) {
    int bh = blockIdx.y; int b = bh / H, h = bh % H;
    int i0 = blockIdx.x * 16;
    int tid = threadIdx.x;
    int d = tid & 63, r0 = tid >> 6;
    __shared__ __align__(16) float Vs[16][68];
    __shared__ float Ps[16][17];
    float acc[4] = {0.f, 0.f, 0.f, 0.f};
    int imax = i0 + 15;
    int lo_tile = (h & 1) ? max(0, i0 - (BAND - 1)) : 0;
    int j_begin = lo_tile & ~15;
    for (int j0 = j_begin; j0 <= imax; j0 += 16) {
        {
            int jr = tid >> 4, d0 = (tid & 15) * 4;
            *(float4*)&Vs[jr][d0] =
                *(const float4*)&qkv[((size_t)(b * T + j0 + jr)) * (3 * D) + 2 * D + h * DH + d0];
            int rr = jr, jc = tid & 15;
            int i = i0 + rr, j = j0 + jc;
            int lo = (h & 1) ? i - (BAND - 1) : 0;
            float p = 0.0f;
            if (j <= i && j >= lo) p = att[(((size_t)(b * H + h) * T + i)) * T + j];
            Ps[rr][jc] = p;
        }
        __syncthreads();
#pragma unroll
        for (int jr = 0; jr < 16; jr++) {
            float vv = Vs[jr][d];
#pragma unroll
            for (int q = 0; q < 4; q++) acc[q] += Ps[r0 * 4 + q][jr] * vv;
        }
        __syncthreads();
    }
#pragma unroll
    for (int q = 0; q < 4; q++) {
        int i = i0 + r0 * 4 + q;
        y[((size_t)(b * T + i)) * D + h * DH + d] = acc[q];
    }
}

// ---------------------------------------------------------------------------
extern "C" void kernel_launch(void* const* d_in, const int* in_sizes, int n_in,
                              void* d_out, int out_size, void* d_ws, size_t ws_size,
                              hipStream_t stream) {
    const int*   idx     = (const int*)d_in[0];
    const float* wte     = (const float*)d_in[1];
    const float* wpe     = (const float*)d_in[2];
    const float* ln1_g   = (const float*)d_in[3];
    const float* ln1_b   = (const float*)d_in[4];
    const float* attn_w  = (const float*)d_in[5];
    const float* attn_b  = (const float*)d_in[6];
    const float* proj_w  = (const float*)d_in[7];
    const float* proj_b  = (const float*)d_in[8];
    const float* dape_gw = (const float*)d_in[9];
    const float* dape_gb = (const float*)d_in[10];
    const float* dape_vw = (const float*)d_in[11];
    const float* dape_vb = (const float*)d_in[12];
    const float* dape_ow = (const float*)d_in[13];
    const float* dape_ob = (const float*)d_in[14];
    const float* ln2_g   = (const float*)d_in[15];
    const float* ln2_b   = (const float*)d_in[16];
    const float* gate_w  = (const float*)d_in[17];
    const float* gate_b  = (const float*)d_in[18];
    const float* val_w   = (const float*)d_in[19];
    const float* val_b   = (const float*)d_in[20];
    const float* mlp_w   = (const float*)d_in[21];
    const float* mlp_b   = (const float*)d_in[22];
    const float* lnf_g   = (const float*)d_in[23];
    const float* lnf_b   = (const float*)d_in[24];
    const float* lm_w    = (const float*)d_in[25];
    float* out = (float*)d_out;

    // Workspace layout (floats): ~109 MB total
    float* ws   = (float*)d_ws;
    float* x    = ws;                            // B*T*D      = 1,048,576
    float* hbuf = x    + (size_t)B * T * D;      // B*T*D
    float* qkv  = hbuf + (size_t)B * T * D;      // B*T*3D     = 3,145,728
    float* att  = qkv  + (size_t)B * T * 3 * D;  // B*H*T*T    = 16,777,216
    float* y    = att  + (size_t)B * H * T * T;  // B*T*D
    float* ff   = y    + (size_t)B * T * D;      // B*T*FF     = 4,194,304

    embed_k<<<B * T, 256, 0, stream>>>(idx, wte, wpe, x);

    for (int l = 0; l < L; l++) {
        ln_k<<<B * T, 256, 0, stream>>>(x, ln1_g + l * D, ln1_b + l * D, hbuf);
        gemm_k<0><<<dim3(3 * D / 64, B * T / 64), 256, 0, stream>>>(
            hbuf, attn_w + (size_t)l * 3 * D * D, attn_b + l * 3 * D, nullptr, qkv, B * T, 3 * D, D);
        qk_k<<<dim3(T / 64, T / 16, B * H), 256, 0, stream>>>(qkv, att);
        dape_k<<<B * T, 256, 0, stream>>>(att,
            dape_gw + l * WD * 2 * H, dape_gb + l * WD,
            dape_vw + l * WD * 2 * H, dape_vb + l * WD,
            dape_ow + l * H * WD, dape_ob + l * H);
        softmax_k<<<B * H * T, 256, 0, stream>>>(att);
        av_k<<<dim3(T / 16, B * H), 256, 0, stream>>>(att, qkv, y);
        gemm_k<1><<<dim3(D / 64, B * T / 64), 256, 0, stream>>>(
            y, proj_w + (size_t)l * D * D, proj_b + l * D, x, x, B * T, D, D);
        ln_k<<<B * T, 256, 0, stream>>>(x, ln2_g + l * D, ln2_b + l * D, hbuf);
        gemm_swiglu_k<<<dim3(FF / 64, B * T / 64), 256, 0, stream>>>(
            hbuf, gate_w + (size_t)l * FF * D, gate_b + l * FF,
            val_w + (size_t)l * FF * D, val_b + l * FF, ff, B * T, FF, D);
        gemm_k<1><<<dim3(D / 64, B * T / 64), 256, 0, stream>>>(
            ff, mlp_w + (size_t)l * D * FF, mlp_b + l * D, x, x, B * T, D, FF);
    }

    ln_k<<<B * T, 256, 0, stream>>>(x, lnf_g, lnf_b, hbuf);
    gemm_k<2><<<dim3(V / 64, B * T / 64), 256, 0, stream>>>(
        hbuf, lm_w, nullptr, nullptr, out, B * T, V, D);
}

// Round 2
// 2598.700 us; speedup vs baseline: 1.5205x; 1.5205x over previous
//
#include <hip/hip_runtime.h>
#include <hip/hip_bf16.h>
#include <math.h>

// Model constants (fixed by the reference)
constexpr int L = 4, D = 512, H = 8, DH = 64, FF = 2048, V = 32000, B = 2, T = 1024, WD = 32, BAND = 128;
constexpr float SCALE = 0.125f;  // 1/sqrt(64)

typedef __hip_bfloat16 bf16;
typedef __attribute__((ext_vector_type(8))) short short8;   // 8 bf16 = 4 VGPRs (MFMA A/B frag)
typedef __attribute__((ext_vector_type(4))) float floatx4;  // MFMA C/D frag

// async global->LDS, 16B per lane; LDS dest = wave-uniform base + lane*16
__device__ inline void gl_lds16(const void* g, void* l) {
    __builtin_amdgcn_global_load_lds((const __attribute__((address_space(1))) unsigned int*)g,
                                     (__attribute__((address_space(3))) unsigned int*)l, 16, 0, 0);
}

// ---------------------------------------------------------------------------
// Embedding: x[b,t,:] = wte[idx[b,t],:] + wpe[t,:]
// ---------------------------------------------------------------------------
__global__ __launch_bounds__(256) void embed_k(const int* __restrict__ idx,
                                               const float* __restrict__ wte,
                                               const float* __restrict__ wpe,
                                               float* __restrict__ x) {
    int row = blockIdx.x;
    int t = row % T;
    int token = idx[row];
    const float* we = wte + (size_t)token * D;
    const float* pe = wpe + (size_t)t * D;
    float* xo = x + (size_t)row * D;
    for (int d = threadIdx.x; d < D; d += 256) xo[d] = we[d] + pe[d];
}

// ---------------------------------------------------------------------------
// fp32 -> bf16 convert (weights), 4 elems/thread
// ---------------------------------------------------------------------------
__global__ __launch_bounds__(256) void f2b_k(const float* __restrict__ in,
                                             bf16* __restrict__ out, int n4) {
    int i = blockIdx.x * 256 + threadIdx.x;
    if (i >= n4) return;
    float4 v = *(const float4*)&in[(size_t)i * 4];
    bf16 o[4] = {__float2bfloat16(v.x), __float2bfloat16(v.y),
                 __float2bfloat16(v.z), __float2bfloat16(v.w)};
    *(ulong1*)&out[(size_t)i * 4] = *(ulong1*)o;
}

// ---------------------------------------------------------------------------
// LayerNorm over D=512, one block (256 thr) per row -> bf16 output
// ---------------------------------------------------------------------------
__global__ __launch_bounds__(256) void ln_bf16_k(const float* __restrict__ x,
                                                 const float* __restrict__ g,
                                                 const float* __restrict__ b,
                                                 bf16* __restrict__ o) {
    int row = blockIdx.x;
    const float* xr = x + (size_t)row * D;
    int d0 = threadIdx.x, d1 = threadIdx.x + 256;
    float v0 = xr[d0], v1 = xr[d1];
    float s = v0 + v1, ss = v0 * v0 + v1 * v1;
    for (int off = 32; off > 0; off >>= 1) {
        s  += __shfl_down(s, off);
        ss += __shfl_down(ss, off);
    }
    __shared__ float red[2][4];
    int wid = threadIdx.x >> 6;
    if ((threadIdx.x & 63) == 0) { red[0][wid] = s; red[1][wid] = ss; }
    __syncthreads();
    s  = red[0][0] + red[0][1] + red[0][2] + red[0][3];
    ss = red[1][0] + red[1][1] + red[1][2] + red[1][3];
    float mean = s * (1.0f / D);
    float var  = ss * (1.0f / D) - mean * mean;
    float rstd = rsqrtf(var + 1e-5f);
    bf16* orow = o + (size_t)row * D;
    orow[d0] = __float2bfloat16((v0 - mean) * rstd * g[d0] + b[d0]);
    orow[d1] = __float2bfloat16((v1 - mean) * rstd * g[d1] + b[d1]);
}

// ---------------------------------------------------------------------------
// bf16 MFMA GEMM: C[m,n] = sum_k A[m,k]*W[n,k] (+bias)(+res), fp32 out.
// 128x128 tile, BK=32, 256 thr = 4 waves (2x2 of 64x64), 16x16x32 MFMA.
// EPI: 0=+bias, 1=+bias+res, 2=plain. M%128==0, N%128==0, K%32==0.
// ---------------------------------------------------------------------------
template <int EPI>
__global__ __launch_bounds__(256) void mgemm_k(const bf16* __restrict__ A,
                                               const bf16* __restrict__ W,
                                               const float* __restrict__ bias,
                                               const float* res,
                                               float* C, int M, int N, int K) {
    __shared__ __align__(16) bf16 As[128 * 32];
    __shared__ __align__(16) bf16 Bs[128 * 32];
    int tid = threadIdx.x;
    int wave = tid >> 6, lane = tid & 63;
    int quad = lane >> 4, l16 = lane & 15;
    int m0 = blockIdx.y * 128, n0 = blockIdx.x * 128;
    int wm = wave >> 1, wn = wave & 1;
    floatx4 acc[4][4] = {};

    // staging: thread tid covers 16B chunk idx (it*256+tid); row=idx>>2, kcol=(idx&3)*8
    int idx0 = tid, idx1 = tid + 256;
    const bf16* Ag0 = A + (size_t)(m0 + (idx0 >> 2)) * K + (idx0 & 3) * 8;
    const bf16* Ag1 = A + (size_t)(m0 + (idx1 >> 2)) * K + (idx1 & 3) * 8;
    const bf16* Wg0 = W + (size_t)(n0 + (idx0 >> 2)) * K + (idx0 & 3) * 8;
    const bf16* Wg1 = W + (size_t)(n0 + (idx1 >> 2)) * K + (idx1 & 3) * 8;
    bf16* lA0 = As + (size_t)(wave * 64) * 8;
    bf16* lA1 = As + (size_t)(256 + wave * 64) * 8;
    bf16* lB0 = Bs + (size_t)(wave * 64) * 8;
    bf16* lB1 = Bs + (size_t)(256 + wave * 64) * 8;

    for (int k0 = 0; k0 < K; k0 += 32) {
        __syncthreads();
        gl_lds16(Ag0 + k0, lA0);
        gl_lds16(Ag1 + k0, lA1);
        gl_lds16(Wg0 + k0, lB0);
        gl_lds16(Wg1 + k0, lB1);
        __syncthreads();
        short8 a[4], b[4];
#pragma unroll
        for (int mi = 0; mi < 4; mi++)
            a[mi] = *(const short8*)&As[(wm * 64 + mi * 16 + l16) * 32 + quad * 8];
#pragma unroll
        for (int ni = 0; ni < 4; ni++)
            b[ni] = *(const short8*)&Bs[(wn * 64 + ni * 16 + l16) * 32 + quad * 8];
#pragma unroll
        for (int mi = 0; mi < 4; mi++)
#pragma unroll
            for (int ni = 0; ni < 4; ni++)
                acc[mi][ni] = __builtin_amdgcn_mfma_f32_16x16x32_bf16(a[mi], b[ni], acc[mi][ni], 0, 0, 0);
    }

    int row_base = m0 + wm * 64 + quad * 4;
    int col_base = n0 + wn * 64 + l16;
#pragma unroll
    for (int mi = 0; mi < 4; mi++) {
#pragma unroll
        for (int r = 0; r < 4; r++) {
            int m = row_base + mi * 16 + r;
            float* Crow = C + (size_t)m * N;
#pragma unroll
            for (int ni = 0; ni < 4; ni++) {
                int n = col_base + ni * 16;
                float v = acc[mi][ni][r];
                if (EPI == 0 || EPI == 1) v += bias[n];
                if (EPI == 1) v += res[(size_t)m * N + n];
                Crow[n] = v;
            }
        }
    }
}

// ---------------------------------------------------------------------------
// SWIGLU elementwise: out = silu(g)*v -> bf16, 4 elems/thread
// ---------------------------------------------------------------------------
__global__ __launch_bounds__(256) void swiglu_k(const float* __restrict__ g,
                                                const float* __restrict__ v,
                                                bf16* __restrict__ out, int n4) {
    int i = blockIdx.x * 256 + threadIdx.x;
    if (i >= n4) return;
    float4 gv = *(const float4*)&g[(size_t)i * 4];
    float4 vv = *(const float4*)&v[(size_t)i * 4];
    float r0 = gv.x / (1.0f + __expf(-gv.x)) * vv.x;
    float r1 = gv.y / (1.0f + __expf(-gv.y)) * vv.y;
    float r2 = gv.z / (1.0f + __expf(-gv.z)) * vv.z;
    float r3 = gv.w / (1.0f + __expf(-gv.w)) * vv.w;
    bf16 o[4] = {__float2bfloat16(r0), __float2bfloat16(r1),
                 __float2bfloat16(r2), __float2bfloat16(r3)};
    *(ulong1*)&out[(size_t)i * 4] = *(ulong1*)o;
}

// ---------------------------------------------------------------------------
// QK^T (fp32): att[b,h,i,j] = SCALE * q_i·k_j for all causal (j<=i), all heads
// ---------------------------------------------------------------------------
__global__ __launch_bounds__(256) void qk_k(const float* __restrict__ qkv,
                                            float* __restrict__ att) {
    int bh = blockIdx.z; int b = bh / H, h = bh % H;
    int i0 = blockIdx.y * 16, j0 = blockIdx.x * 64;
    if (j0 > i0 + 15) return;
    __shared__ __align__(16) float Qs[16][68];
    __shared__ __align__(16) float Ks[64][68];
    int tid = threadIdx.x;
    {
        int r = tid >> 4, d0 = (tid & 15) * 4;
        *(float4*)&Qs[r][d0] = *(const float4*)&qkv[((size_t)(b * T + i0 + r)) * (3 * D) + h * DH + d0];
#pragma unroll
        for (int it = 0; it < 4; it++) {
            int c = (tid >> 4) + it * 16;
            *(float4*)&Ks[c][d0] = *(const float4*)&qkv[((size_t)(b * T + j0 + c)) * (3 * D) + D + h * DH + d0];
        }
    }
    __syncthreads();
    int c = tid & 63;
    int r0 = tid >> 6;
    float acc[4] = {0.f, 0.f, 0.f, 0.f};
#pragma unroll
    for (int d0 = 0; d0 < 64; d0 += 4) {
        float4 kv = *(const float4*)&Ks[c][d0];
#pragma unroll
        for (int q = 0; q < 4; q++) {
            float4 qv = *(const float4*)&Qs[r0 * 4 + q][d0];
            acc[q] += qv.x * kv.x + qv.y * kv.y + qv.z * kv.z + qv.w * kv.w;
        }
    }
    size_t base = ((size_t)(b * H + h) * T) * T;
#pragma unroll
    for (int q = 0; q < 4; q++) {
        int i = i0 + r0 * 4 + q, j = j0 + c;
        if (j <= i) att[base + (size_t)i * T + j] = acc[q] * SCALE;
    }
}

// ---------------------------------------------------------------------------
// DAPE + ALiBi in place on raw scores
// ---------------------------------------------------------------------------
__global__ __launch_bounds__(256) void dape_k(float* __restrict__ att,
                                              const float* __restrict__ gw,
                                              const float* __restrict__ gb,
                                              const float* __restrict__ vw,
                                              const float* __restrict__ vb,
                                              const float* __restrict__ ow,
                                              const float* __restrict__ ob) {
    int bi = blockIdx.x; int b = bi / T, i = bi % T;
    __shared__ float sgw[WD][H], svw[WD][H], sow[H][WD];
    __shared__ float sgb[WD], svb[WD], sob[H];
    int tid = threadIdx.x;
    if (tid < WD * H) {
        int w = tid >> 3, hh = tid & 7;
        sgw[w][hh] = gw[w * (2 * H) + hh];
        svw[w][hh] = vw[w * (2 * H) + hh];
        sow[hh][w] = ow[hh * WD + w];
    }
    if (tid < WD) { sgb[tid] = gb[tid]; svb[tid] = vb[tid]; }
    if (tid < H) sob[tid] = ob[tid];
    __syncthreads();
    const float slopes[H] = {0.5f, 0.25f, 0.125f, 0.0625f, 0.03125f, 0.015625f, 0.0078125f, 0.00390625f};
    size_t base = (size_t)b * H * T * T + (size_t)i * T;
    for (int j = tid; j <= i; j += 256) {
        float s[H], lb[H];
#pragma unroll
        for (int hh = 0; hh < H; hh++) s[hh] = att[base + (size_t)hh * T * T + j];
#pragma unroll
        for (int hh = 0; hh < H; hh++) lb[hh] = sob[hh];
#pragma unroll
        for (int w = 0; w < WD; w++) {
            float g = sgb[w], v = svb[w];
#pragma unroll
            for (int hh = 0; hh < H; hh++) { g += s[hh] * sgw[w][hh]; v += s[hh] * svw[w][hh]; }
            float hid = (g / (1.0f + __expf(-g))) * v;
#pragma unroll
            for (int hh = 0; hh < H; hh++) lb[hh] += hid * sow[hh][w];
        }
        float diff = (float)(i - j);
#pragma unroll
        for (int hh = 0; hh < H; hh++)
            att[base + (size_t)hh * T * T + j] = s[hh] + lb[hh] - slopes[hh] * diff;
    }
}

// ---------------------------------------------------------------------------
// Row softmax over valid range: even h -> [0,i]; odd h -> [max(0,i-127), i]
// ---------------------------------------------------------------------------
__global__ __launch_bounds__(256) void softmax_k(float* __restrict__ att) {
    int id = blockIdx.x;
    int i = id % T;
    int h = (id / T) % H;
    size_t base = (size_t)id * T;
    int jlo = (h & 1) ? max(0, i - (BAND - 1)) : 0;
    int tid = threadIdx.x;
    float mx = -1e30f;
    for (int j = jlo + tid; j <= i; j += 256) mx = fmaxf(mx, att[base + j]);
    for (int off = 32; off > 0; off >>= 1) mx = fmaxf(mx, __shfl_down(mx, off));
    __shared__ float redm[4], reds[4];
    if ((tid & 63) == 0) redm[tid >> 6] = mx;
    __syncthreads();
    mx = fmaxf(fmaxf(redm[0], redm[1]), fmaxf(redm[2], redm[3]));
    float sum = 0.f;
    for (int j = jlo + tid; j <= i; j += 256) {
        float e = __expf(att[base + j] - mx);
        att[base + j] = e;
        sum += e;
    }
    for (int off = 32; off > 0; off >>= 1) sum += __shfl_down(sum, off);
    if ((tid & 63) == 0) reds[tid >> 6] = sum;
    __syncthreads();
    sum = reds[0] + reds[1] + reds[2] + reds[3];
    float inv = 1.0f / sum;
    for (int j = jlo + tid; j <= i; j += 256) att[base + j] *= inv;
}

// ---------------------------------------------------------------------------
// AV (fp32 in, bf16 out): y[b,i,h*64+d] = sum_j p[b,h,i,j]*v[b,j,h,d]
// ---------------------------------------------------------------------------
__global__ __launch_bounds__(256) void av_k(const float* __restrict__ att,
                                            const float* __restrict__ qkv,
                                            bf16* __restrict__ y) {
    int bh = blockIdx.y; int b = bh / H, h = bh % H;
    int i0 = blockIdx.x * 16;
    int tid = threadIdx.x;
    int d = tid & 63, r0 = tid >> 6;
    __shared__ __align__(16) float Vs[16][68];
    __shared__ float Ps[16][17];
    float acc[4] = {0.f, 0.f, 0.f, 0.f};
    int imax = i0 + 15;
    int lo_tile = (h & 1) ? max(0, i0 - (BAND - 1)) : 0;
    int j_begin = lo_tile & ~15;
    for (int j0 = j_begin; j0 <= imax; j0 += 16) {
        {
            int jr = tid >> 4, d0 = (tid & 15) * 4;
            *(float4*)&Vs[jr][d0] =
                *(const float4*)&qkv[((size_t)(b * T + j0 + jr)) * (3 * D) + 2 * D + h * DH + d0];
            int rr = jr, jc = tid & 15;
            int i = i0 + rr, j = j0 + jc;
            int lo = (h & 1) ? i - (BAND - 1) : 0;
            float p = 0.0f;
            if (j <= i && j >= lo) p = att[(((size_t)(b * H + h) * T + i)) * T + j];
            Ps[rr][jc] = p;
        }
        __syncthreads();
#pragma unroll
        for (int jr = 0; jr < 16; jr++) {
            float vv = Vs[jr][d];
#pragma unroll
            for (int q = 0; q < 4; q++) acc[q] += Ps[r0 * 4 + q][jr] * vv;
        }
        __syncthreads();
    }
#pragma unroll
    for (int q = 0; q < 4; q++) {
        int i = i0 + r0 * 4 + q;
        y[((size_t)(b * T + i)) * D + h * DH + d] = __float2bfloat16(acc[q]);
    }
}

// ---------------------------------------------------------------------------
extern "C" void kernel_launch(void* const* d_in, const int* in_sizes, int n_in,
                              void* d_out, int out_size, void* d_ws, size_t ws_size,
                              hipStream_t stream) {
    const int*   idx     = (const int*)d_in[0];
    const float* wte     = (const float*)d_in[1];
    const float* wpe     = (const float*)d_in[2];
    const float* ln1_g   = (const float*)d_in[3];
    const float* ln1_b   = (const float*)d_in[4];
    const float* attn_w  = (const float*)d_in[5];
    const float* attn_b  = (const float*)d_in[6];
    const float* proj_w  = (const float*)d_in[7];
    const float* proj_b  = (const float*)d_in[8];
    const float* dape_gw = (const float*)d_in[9];
    const float* dape_gb = (const float*)d_in[10];
    const float* dape_vw = (const float*)d_in[11];
    const float* dape_vb = (const float*)d_in[12];
    const float* dape_ow = (const float*)d_in[13];
    const float* dape_ob = (const float*)d_in[14];
    const float* ln2_g   = (const float*)d_in[15];
    const float* ln2_b   = (const float*)d_in[16];
    const float* gate_w  = (const float*)d_in[17];
    const float* gate_b  = (const float*)d_in[18];
    const float* val_w   = (const float*)d_in[19];
    const float* val_b   = (const float*)d_in[20];
    const float* mlp_w   = (const float*)d_in[21];
    const float* mlp_b   = (const float*)d_in[22];
    const float* lnf_g   = (const float*)d_in[23];
    const float* lnf_b   = (const float*)d_in[24];
    const float* lm_w    = (const float*)d_in[25];
    float* out = (float*)d_out;

    // Workspace layout (~163 MB): fp32 region then bf16 region.
    // gbuf/vbuf alias att: att is dead between av_k (end of attn) and next qk_k.
    float* ws   = (float*)d_ws;
    float* x    = ws;                            // B*T*D
    float* qkv  = x    + (size_t)B * T * D;      // B*T*3D
    float* att  = qkv  + (size_t)B * T * 3 * D;  // B*H*T*T
    float* gbuf = att;                           // alias, B*T*FF
    float* vbuf = att  + (size_t)B * T * FF;     // alias, B*T*FF
    bf16*  hb   = (bf16*)(att + (size_t)B * H * T * T);  // B*T*D
    bf16*  yb   = hb  + (size_t)B * T * D;               // B*T*D
    bf16*  ffb  = yb  + (size_t)B * T * D;               // B*T*FF
    bf16*  wq   = ffb + (size_t)B * T * FF;              // L*3D*D
    bf16*  wp   = wq  + (size_t)L * 3 * D * D;           // L*D*D
    bf16*  wg   = wp  + (size_t)L * D * D;               // L*FF*D
    bf16*  wv   = wg  + (size_t)L * FF * D;              // L*FF*D
    bf16*  wm   = wv  + (size_t)L * FF * D;              // L*D*FF
    bf16*  wl   = wm  + (size_t)L * D * FF;              // V*D

    // weight conversion (every launch; weights restored by harness each call)
    auto conv = [&](const float* src, bf16* dst, size_t n) {
        int n4 = (int)(n / 4);
        f2b_k<<<(n4 + 255) / 256, 256, 0, stream>>>(src, dst, n4);
    };
    conv(attn_w, wq, (size_t)L * 3 * D * D);
    conv(proj_w, wp, (size_t)L * D * D);
    conv(gate_w, wg, (size_t)L * FF * D);
    conv(val_w,  wv, (size_t)L * FF * D);
    conv(mlp_w,  wm, (size_t)L * D * FF);
    conv(lm_w,   wl, (size_t)V * D);

    embed_k<<<B * T, 256, 0, stream>>>(idx, wte, wpe, x);

    const int M = B * T;
    for (int l = 0; l < L; l++) {
        ln_bf16_k<<<M, 256, 0, stream>>>(x, ln1_g + l * D, ln1_b + l * D, hb);
        mgemm_k<0><<<dim3(3 * D / 128, M / 128), 256, 0, stream>>>(
            hb, wq + (size_t)l * 3 * D * D, attn_b + l * 3 * D, nullptr, qkv, M, 3 * D, D);
        qk_k<<<dim3(T / 64, T / 16, B * H), 256, 0, stream>>>(qkv, att);
        dape_k<<<B * T, 256, 0, stream>>>(att,
            dape_gw + l * WD * 2 * H, dape_gb + l * WD,
            dape_vw + l * WD * 2 * H, dape_vb + l * WD,
            dape_ow + l * H * WD, dape_ob + l * H);
        softmax_k<<<B * H * T, 256, 0, stream>>>(att);
        av_k<<<dim3(T / 16, B * H), 256, 0, stream>>>(att, qkv, yb);
        mgemm_k<1><<<dim3(D / 128, M / 128), 256, 0, stream>>>(
            yb, wp + (size_t)l * D * D, proj_b + l * D, x, x, M, D, D);
        ln_bf16_k<<<M, 256, 0, stream>>>(x, ln2_g + l * D, ln2_b + l * D, hb);
        mgemm_k<0><<<dim3(FF / 128, M / 128), 256, 0, stream>>>(
            hb, wg + (size_t)l * FF * D, gate_b + l * FF, nullptr, gbuf, M, FF, D);
        mgemm_k<0><<<dim3(FF / 128, M / 128), 256, 0, stream>>>(
            hb, wv + (size_t)l * FF * D, val_b + l * FF, nullptr, vbuf, M, FF, D);
        {
            int n4 = B * T * FF / 4;
            swiglu_k<<<(n4 + 255) / 256, 256, 0, stream>>>(gbuf, vbuf, ffb, n4);
        }
        mgemm_k<1><<<dim3(D / 128, M / 128), 256, 0, stream>>>(
            ffb, wm + (size_t)l * D * FF, mlp_b + l * D, x, x, M, D, FF);
    }

    ln_bf16_k<<<M, 256, 0, stream>>>(x, lnf_g, lnf_b, hb);
    mgemm_k<2><<<dim3(V / 128, M / 128), 256, 0, stream>>>(
        hb, wl, nullptr, nullptr, out, M, V, D);
}